// Round 5
// baseline (358.431 us; speedup 1.0000x reference)
//
#include <hip/hip_runtime.h>

#define B_    32
#define S_    4096
#define CIN_  7
#define NF_   35      // 5 * CIN
#define D_    512
#define WIN_  24
#define K3_   105     // NF * 3 (GEMM K)
#define P_    120     // LDS F row stride in bf16 elems (mult of 8, not pow2)
#define QN_   66      // tap positions per s-tile: s0-1 .. s0+64
#define TPB_  4       // s-tiles per block
#define NG_   16      // tile groups = 64 / TPB_
#define XDW_  640     // raw x dwords staged per tile (need 89*7 = 623)
#define FSZ_  (64 * P_ + 8)   // F buffer size: +8 tail so the (row63,ks3,lq3)
                              // short8 fragment read stays in-bounds & zeroed

typedef __attribute__((ext_vector_type(8))) short short8;   // 8 x bf16 (4 VGPR)
typedef __attribute__((ext_vector_type(4))) float float4_;  // MFMA C/D

__device__ __forceinline__ unsigned short f2bf(float f) {
    unsigned int u = __builtin_bit_cast(unsigned int, f);
    u += 0x7FFFu + ((u >> 16) & 1u);          // RNE to bf16
    return (unsigned short)(u >> 16);
}

// ---------------------------------------------------------------------------
// Pack W (512, 35, 3) fp32 -> bf16 A-operand fragments, fragment-linear:
//   slot(nsub 0..31, kstep 0..3, lane 0..63) holds 8 bf16:
//     Wt[d = nsub*16 + (lane&15)][k = kstep*32 + (lane>>4)*8 + j], j=0..7
//     (zero-padded for k >= 105)
// ---------------------------------------------------------------------------
__global__ __launch_bounds__(256) void pack_w_kernel(
    const float* __restrict__ W, short* __restrict__ Bf)
{
    const int slot = blockIdx.x * 256 + threadIdx.x;   // 0..8191
    if (slot >= 32 * 4 * 64) return;
    const int l     = slot & 63;
    const int kstep = (slot >> 6) & 3;
    const int nsub  = slot >> 8;
    const int d  = nsub * 16 + (l & 15);
    const int kb = kstep * 32 + (l >> 4) * 8;

    short8 v;
    #pragma unroll
    for (int j = 0; j < 8; ++j) {
        const int kappa = kb + j;
        v[j] = (kappa < K3_) ? (short)f2bf(W[(size_t)d * K3_ + kappa]) : (short)0;
    }
    *(short8*)(Bf + (size_t)slot * 8) = v;
}

// ---------------------------------------------------------------------------
// Rolling-stats core: identical arithmetic to the verified kernel.
// ---------------------------------------------------------------------------
__device__ __forceinline__ void stats_core_store(
    const float v[WIN_], int q, int f, short* __restrict__ sF)
{
    float sum = 0.f, mx = v[0], mn = v[0];
    #pragma unroll
    for (int j = 0; j < WIN_; ++j) {
        sum += v[j];
        mx = fmaxf(mx, v[j]);
        mn = fminf(mn, v[j]);
    }
    const float mean = sum * (1.0f / WIN_);
    float var = 0.f;
    #pragma unroll
    for (int j = 0; j < WIN_; ++j) {
        const float dv = v[j] - mean;
        var = fmaf(dv, dv, var);
    }
    const float sd = sqrtf(var * (1.0f / (WIN_ - 1)) + 1e-12f);

    const float vals[5] = { v[WIN_ - 1], mean, mx, mn, sd };
    // F[m][kappa = i*3 + k] = tap[i][q] with m = q - k
    #pragma unroll
    for (int k = 0; k < 3; ++k) {
        const int m = q - k;
        if (m >= 0 && m < 64) {
            #pragma unroll
            for (int gg = 0; gg < 5; ++gg) {
                const int i = f + gg * CIN_;
                sF[m * P_ + i * 3 + k] = (short)f2bf(vals[gg]);
            }
        }
    }
}

// Slow path: direct global loads, circular tap + front-clamped window.
// Used for the first tile of each block and for tile 63 (wrap cases).
__device__ __forceinline__ void stats_direct(
    const float* __restrict__ xb, int s0, int tid, short* __restrict__ sF)
{
    if (tid < QN_ * CIN_) {
        const int q = tid / CIN_;
        const int f = tid - q * CIN_;
        int p = s0 - 1 + q;
        const int sm = p < 0 ? p + S_ : (p >= S_ ? p - S_ : p);
        const float* xp = xb + f;
        float v[WIN_];
        #pragma unroll
        for (int j = 0; j < WIN_; ++j) {
            int sc = sm - (WIN_ - 1) + j;
            sc = sc < 0 ? 0 : sc;
            v[j] = xp[(size_t)sc * CIN_];
        }
        stats_core_store(v, q, f, sF);
    }
}

// Fast path: windows read from the LDS-staged raw x tile.
// sX[r*7+f] = x[b][s0-24+r][f]; tap q window elem j is row r = q + j.
// Valid only when no circular wrap / front clamp touches the tile
// (tile index 1..62), which the caller guarantees.
__device__ __forceinline__ void stats_fast(
    const float* __restrict__ sX, int tid, short* __restrict__ sF)
{
    if (tid < QN_ * CIN_) {
        const int q = tid / CIN_;
        const int f = tid - q * CIN_;
        float v[WIN_];
        #pragma unroll
        for (int j = 0; j < WIN_; ++j)
            v[j] = sX[(q + j) * CIN_ + f];
        stats_core_store(v, q, f, sF);
    }
}

// ---------------------------------------------------------------------------
// Persistent multi-tile pipelined kernel.
// Grid (16, 32): 512 blocks x 512 threads = 2 blocks/CU fully resident.
// Each block processes TPB_=4 consecutive s-tiles of 64 rows:
//   iter it: [issue next tile's raw x loads to regs] -> MFMA GEMM on sF[buf]
//            -> epilogue stores -> ds_write raw x to sX (vmcnt hides under
//            MFMA/stores) -> barrier -> stats from sX into sF[buf^1] -> barrier
// Double-buffered F tiles; raw-x staging is contiguous (coalesced) for
// interior tiles; tiles 0 and 63 use the direct-global stats path.
//
// NaN fix (round 3 post-mortem): F-fragment short8 reads at (row 63, ks=3,
// lq=3) start at element 64*P_ and cover 8 shorts past the nominal 64*P_
// region (fragments span k=0..127, row stride is 120). Buffers are therefore
// FSZ_ = 64*P_+8 with a zeroed tail, so k>=105 products are 0*0 = 0 in both
// buffers at every iteration (previously this read uninitialized LDS).
// ---------------------------------------------------------------------------
template <bool USE_WS>
__global__ __launch_bounds__(512, 4) void fused_pipe_kernel(
    const float* __restrict__ x, const float* __restrict__ W,
    const short* __restrict__ Bf, const float* __restrict__ bias,
    float* __restrict__ out)
{
    __shared__ short sF[2][FSZ_];        // double-buffered F[s'][kappa], bf16
    __shared__ float sX[XDW_];           // raw x rows for the NEXT tile

    const int tid   = threadIdx.x;
    const int grp   = blockIdx.x;        // tile group 0..15
    const int b     = blockIdx.y;
    const int tile0 = grp * TPB_;
    const float* xb = x + (size_t)b * S_ * CIN_;

    // zero the K padding (kappa 105..119) of BOTH buffers once; stats only
    // ever write kappa < 105, so this persists across the tile loop.
    for (int t = tid; t < 2 * 64 * (P_ - K3_); t += 512) {
        const int bufz = t / (64 * (P_ - K3_));
        const int r    = t - bufz * (64 * (P_ - K3_));
        const int m    = r / (P_ - K3_);
        const int c    = K3_ + (r - m * (P_ - K3_));
        sF[bufz][m * P_ + c] = 0;
    }
    // zero the 8-short tails (the row-63 fragment overflow region)
    if (tid < 16) sF[tid >> 3][64 * P_ + (tid & 7)] = 0;

    // prologue: F for the block's first tile (handles tile 0's wrap/clamp)
    stats_direct(xb, tile0 * 64, tid, sF[0]);
    __syncthreads();

    const int w  = tid >> 6;          // wave id 0..7 -> d base = w*64
    const int l  = tid & 63;
    const int lr = l & 15;            // 16-index: F row (s') / W row (d')
    const int lq = l >> 4;            // quad

    float4_ bias4[4];                 // persistent across tiles
    #pragma unroll
    for (int n = 0; n < 4; ++n)
        bias4[n] = *(const float4_*)(bias + w * 64 + n * 16 + lq * 4);

    for (int it = 0; it < TPB_; ++it) {
        const int  buf       = it & 1;
        const int  s0        = (tile0 + it) * 64;
        const bool has_next  = (it + 1 < TPB_);
        const bool next_fast = has_next && (tile0 + it + 1 <= 62);

        // ---- issue next tile's raw x loads EARLY (latency hides below) ----
        float tmp0 = 0.f, tmp1 = 0.f;
        const float* xs = xb + (size_t)(s0 + 64 - WIN_) * CIN_;   // row s0n-24
        if (next_fast) {
            tmp0 = xs[tid];
            if (tid < XDW_ - 512) tmp1 = xs[512 + tid];
        }

        // ---- MFMA GEMM on sF[buf] (W as A-operand, F as B-operand) ----
        float4_ acc[4][4];
        #pragma unroll
        for (int n = 0; n < 4; ++n)
            #pragma unroll
            for (int m = 0; m < 4; ++m) acc[m][n] = bias4[n];

        #pragma unroll
        for (int ks = 0; ks < 4; ++ks) {
            short8 ff[4];
            #pragma unroll
            for (int m = 0; m < 4; ++m)
                ff[m] = *(const short8*)&sF[buf][(m * 16 + lr) * P_ + ks * 32 + lq * 8];

            short8 wf[4];
            #pragma unroll
            for (int n = 0; n < 4; ++n) {
                if (USE_WS) {
                    const int nsub = w * 4 + n;
                    wf[n] = *(const short8*)(Bf + ((size_t)(nsub * 4 + ks) * 64 + l) * 8);
                } else {
                    const int d  = w * 64 + n * 16 + lr;
                    const int kb = ks * 32 + lq * 8;
                    short8 t8;
                    #pragma unroll
                    for (int j = 0; j < 8; ++j)
                        t8[j] = (kb + j < K3_) ? (short)f2bf(W[(size_t)d * K3_ + kb + j])
                                               : (short)0;
                    wf[n] = t8;
                }
            }

            #pragma unroll
            for (int m = 0; m < 4; ++m)
                #pragma unroll
                for (int n = 0; n < 4; ++n)
                    acc[m][n] = __builtin_amdgcn_mfma_f32_16x16x32_bf16(
                        wf[n], ff[m], acc[m][n], 0, 0, 0);
        }

        // ---- Epilogue: D row = d' = lq*4+r, col = s' = lr; float4 stores ----
        #pragma unroll
        for (int m = 0; m < 4; ++m) {
            float* ob = out + ((size_t)(b * S_ + s0 + m * 16 + lr)) * D_
                            + w * 64 + lq * 4;
            #pragma unroll
            for (int n = 0; n < 4; ++n)
                *(float4_*)(ob + n * 16) = acc[m][n];
        }

        // ---- stage raw x to LDS, then stats for tile it+1 ----
        if (has_next) {
            if (next_fast) {
                sX[tid] = tmp0;                       // waits tmp0 (vmcnt skips
                if (tid < XDW_ - 512) sX[512 + tid] = tmp1;  // younger stores)
            }
            __syncthreads();                          // sX visible block-wide
            if (next_fast) stats_fast(sX, tid, sF[buf ^ 1]);
            else           stats_direct(xb, s0 + 64, tid, sF[buf ^ 1]);  // tile 63
            __syncthreads();                          // sF[buf^1] ready
        }
    }
}

// ---------------------------------------------------------------------------
extern "C" void kernel_launch(void* const* d_in, const int* in_sizes, int n_in,
                              void* d_out, int out_size, void* d_ws, size_t ws_size,
                              hipStream_t stream) {
    const float* x      = (const float*)d_in[0];   // (32, 4096, 7)
    // d_in[1] = x_mark: unused by the reference
    const float* W_conv = (const float*)d_in[2];   // (512, 35, 3)
    const float* b_conv = (const float*)d_in[3];   // (512,)
    float* out = (float*)d_out;                    // (32, 4096, 512)

    const size_t bf_bytes = (size_t)32 * 4 * 64 * 8 * sizeof(short);  // 128 KiB

    if (ws_size >= bf_bytes) {
        short* Bf = (short*)d_ws;
        pack_w_kernel<<<dim3(32), dim3(256), 0, stream>>>(W_conv, Bf);
        fused_pipe_kernel<true><<<dim3(NG_, B_), dim3(512), 0, stream>>>(
            x, W_conv, Bf, b_conv, out);
    } else {
        fused_pipe_kernel<false><<<dim3(NG_, B_), dim3(512), 0, stream>>>(
            x, W_conv, nullptr, b_conv, out);
    }
}

// Round 6
// 300.886 us; speedup vs baseline: 1.1913x; 1.1913x over previous
//
#include <hip/hip_runtime.h>

#define B_    32
#define S_    4096
#define CIN_  7
#define NF_   35      // 5 * CIN
#define D_    512
#define WIN_  24
#define K3_   105     // NF * 3 (GEMM K)
#define P_    120     // LDS F row stride in bf16 elems (mult of 8, not pow2)
#define TS_   32      // s-tile rows per block
#define QN_   34      // tap positions per s-tile: s0-1 .. s0+32  (TS_+2)
#define FSZ_  (TS_ * P_ + 8)  // +8 tail: (row31,ks3,lq3) short8 read ends at
                              // 32*P_+8 (fragments span k=0..127, stride 120)

typedef __attribute__((ext_vector_type(8))) short short8;   // 8 x bf16 (4 VGPR)
typedef __attribute__((ext_vector_type(4))) float float4_;  // MFMA C/D

__device__ __forceinline__ unsigned short f2bf(float f) {
    unsigned int u = __builtin_bit_cast(unsigned int, f);
    u += 0x7FFFu + ((u >> 16) & 1u);          // RNE to bf16
    return (unsigned short)(u >> 16);
}

// ---------------------------------------------------------------------------
// Pack W (512, 35, 3) fp32 -> bf16 A-operand fragments, fragment-linear:
//   slot(nsub 0..31, kstep 0..3, lane 0..63) holds 8 bf16:
//     Wt[d = nsub*16 + (lane&15)][k = kstep*32 + (lane>>4)*8 + j], j=0..7
//     (zero-padded for k >= 105)
// Unchanged from the verified round-1 kernel.
// ---------------------------------------------------------------------------
__global__ __launch_bounds__(256) void pack_w_kernel(
    const float* __restrict__ W, short* __restrict__ Bf)
{
    const int slot = blockIdx.x * 256 + threadIdx.x;   // 0..8191
    if (slot >= 32 * 4 * 64) return;
    const int l     = slot & 63;
    const int kstep = (slot >> 6) & 3;
    const int nsub  = slot >> 8;
    const int d  = nsub * 16 + (l & 15);
    const int kb = kstep * 32 + (l >> 4) * 8;

    short8 v;
    #pragma unroll
    for (int j = 0; j < 8; ++j) {
        const int kappa = kb + j;
        v[j] = (kappa < K3_) ? (short)f2bf(W[(size_t)d * K3_ + kappa]) : (short)0;
    }
    *(short8*)(Bf + (size_t)slot * 8) = v;
}

// ---------------------------------------------------------------------------
// Fused kernel: rolling stats -> bf16 F-tile in LDS -> MFMA GEMM -> out.
// Block: 256 threads = 4 waves; blockIdx = (s-tile of 32, b); grid (128, 32)
// = 4096 blocks -> 16/CU queued, ~4 resident (vs round-1's 2 blocks of 512):
// finer-grained inter-block overlap of stats / MFMA / store phases.
// Wave w covers d = w*128 .. w*128+127 as a 2x8 grid of 16x16x32 bf16 MFMAs
// (m = s-subtile 0..1, n = d-subtile 0..7).
//
// Operand order: mfma(Wfrag, Ffrag) -> D[row = d' = quad*4+reg][col = s'],
// giving float4 (4 consecutive d) epilogue stores. Fragment layouts and
// stats arithmetic byte-identical to the verified round-1 kernel.
// ---------------------------------------------------------------------------
template <bool USE_WS>
__global__ __launch_bounds__(256, 4) void fused_mfma_kernel(
    const float* __restrict__ x, const float* __restrict__ W,
    const short* __restrict__ Bf, const float* __restrict__ bias,
    float* __restrict__ out)
{
    __shared__ short sF[FSZ_];           // F[s'=0..31][kappa], bf16 bits

    const int tid = threadIdx.x;
    const int s0  = blockIdx.x * TS_;
    const int b   = blockIdx.y;

    // ---- Phase 1: stats for taps q=0..33 (s = s0-1+q circular), to LDS ----
    if (tid < QN_ * CIN_) {              // 238 of 256 threads
        const int q = tid / CIN_;
        const int f = tid - q * CIN_;
        int p = s0 - 1 + q;
        const int sm = p < 0 ? p + S_ : (p >= S_ ? p - S_ : p);
        const float* xb = x + (size_t)b * S_ * CIN_ + f;

        float v[WIN_];
        #pragma unroll
        for (int j = 0; j < WIN_; ++j) {
            int sc = sm - (WIN_ - 1) + j;    // front-clamped window
            sc = sc < 0 ? 0 : sc;
            v[j] = xb[(size_t)sc * CIN_];
        }
        float sum = 0.f, mx = v[0], mn = v[0];
        #pragma unroll
        for (int j = 0; j < WIN_; ++j) {
            sum += v[j];
            mx = fmaxf(mx, v[j]);
            mn = fminf(mn, v[j]);
        }
        const float mean = sum * (1.0f / WIN_);
        float var = 0.f;
        #pragma unroll
        for (int j = 0; j < WIN_; ++j) {
            const float dv = v[j] - mean;
            var = fmaf(dv, dv, var);
        }
        const float sd = sqrtf(var * (1.0f / (WIN_ - 1)) + 1e-12f);

        const float vals[5] = { v[WIN_ - 1], mean, mx, mn, sd };
        // F[m][kappa = i*3 + k] = tap[i][q] with m = q - k
        #pragma unroll
        for (int k = 0; k < 3; ++k) {
            const int m = q - k;
            if (m >= 0 && m < TS_) {
                #pragma unroll
                for (int g = 0; g < 5; ++g) {
                    const int i = f + g * CIN_;
                    sF[m * P_ + i * 3 + k] = (short)f2bf(vals[g]);
                }
            }
        }
    }
    // zero the K padding (kappa 105..119): 32*15 = 480 elems, 2 per thread
    for (int t = tid; t < TS_ * (P_ - K3_); t += 256) {
        const int m = t / (P_ - K3_);
        const int c = K3_ + (t - m * (P_ - K3_));
        sF[m * P_ + c] = 0;
    }
    // zero the 8-short tail (row-31 fragment overflow region)
    if (tid < 8) sF[TS_ * P_ + tid] = 0;
    __syncthreads();

    // ---- Phase 2: MFMA GEMM (W as A-operand, F as B-operand) ----
    const int w  = tid >> 6;          // wave id 0..3 -> d base = w*128
    const int l  = tid & 63;
    const int lr = l & 15;            // 16-index: F row (s') / W row (d')
    const int lq = l >> 4;            // quad

    float4_ acc[2][8];                // [m = s-subtile][n = d-subtile]
    #pragma unroll
    for (int n = 0; n < 8; ++n) {
        // bias for d = w*128 + n*16 + lq*4 + r, r=0..3 -> one float4 load
        const float4_ bv = *(const float4_*)(bias + w * 128 + n * 16 + lq * 4);
        acc[0][n] = bv;
        acc[1][n] = bv;
    }

    #pragma unroll
    for (int ks = 0; ks < 4; ++ks) {
        // F fragments (B-operand): lane holds s'=lr, k=ks*32+lq*8+j
        short8 ff[2];
        #pragma unroll
        for (int m = 0; m < 2; ++m)
            ff[m] = *(const short8*)&sF[(m * 16 + lr) * P_ + ks * 32 + lq * 8];

        #pragma unroll
        for (int n = 0; n < 8; ++n) {
            // W fragment (A-operand): lane holds d'=lr, k=ks*32+lq*8+j
            short8 wf;
            if (USE_WS) {
                const int nsub = w * 8 + n;
                wf = *(const short8*)(Bf + ((size_t)(nsub * 4 + ks) * 64 + l) * 8);
            } else {
                const int d  = w * 128 + n * 16 + lr;
                const int kb = ks * 32 + lq * 8;
                short8 t8;
                #pragma unroll
                for (int j = 0; j < 8; ++j)
                    t8[j] = (kb + j < K3_) ? (short)f2bf(W[(size_t)d * K3_ + kb + j])
                                           : (short)0;
                wf = t8;
            }
            acc[0][n] = __builtin_amdgcn_mfma_f32_16x16x32_bf16(
                wf, ff[0], acc[0][n], 0, 0, 0);
            acc[1][n] = __builtin_amdgcn_mfma_f32_16x16x32_bf16(
                wf, ff[1], acc[1][n], 0, 0, 0);
        }
    }

    // ---- Epilogue: D row = d' = lq*4+r, col = s' = lr; float4 stores ----
    #pragma unroll
    for (int m = 0; m < 2; ++m) {
        float* ob = out + ((size_t)(b * S_ + s0 + m * 16 + lr)) * D_
                        + w * 128 + lq * 4;
        #pragma unroll
        for (int n = 0; n < 8; ++n)
            *(float4_*)(ob + n * 16) = acc[m][n];
    }
}

// ---------------------------------------------------------------------------
extern "C" void kernel_launch(void* const* d_in, const int* in_sizes, int n_in,
                              void* d_out, int out_size, void* d_ws, size_t ws_size,
                              hipStream_t stream) {
    const float* x      = (const float*)d_in[0];   // (32, 4096, 7)
    // d_in[1] = x_mark: unused by the reference
    const float* W_conv = (const float*)d_in[2];   // (512, 35, 3)
    const float* b_conv = (const float*)d_in[3];   // (512,)
    float* out = (float*)d_out;                    // (32, 4096, 512)

    const size_t bf_bytes = (size_t)32 * 4 * 64 * 8 * sizeof(short);  // 128 KiB

    if (ws_size >= bf_bytes) {
        short* Bf = (short*)d_ws;
        pack_w_kernel<<<dim3(32), dim3(256), 0, stream>>>(W_conv, Bf);
        fused_mfma_kernel<true><<<dim3(S_ / TS_, B_), dim3(256), 0, stream>>>(
            x, W_conv, Bf, b_conv, out);
    } else {
        fused_mfma_kernel<false><<<dim3(S_ / TS_, B_), dim3(256), 0, stream>>>(
            x, W_conv, nullptr, b_conv, out);
    }
}